// Round 4
// baseline (172.226 us; speedup 1.0000x reference)
//
#include <hip/hip_runtime.h>
#include <cstdint>

// Problem constants (fixed by reference)
#define NT 3200   // B*N
#define NN 100    // N
#define FD 10     // F_IN
#define DD 64     // D

// ---------------- threefry2x32 (JAX PRNG), host+device ----------------
__host__ __device__ inline void tf2x32(uint32_t ks0, uint32_t ks1, uint32_t x0,
                                       uint32_t x1, uint32_t& o0, uint32_t& o1) {
  uint32_t ks2 = ks0 ^ ks1 ^ 0x1BD11BDAu;
  x0 += ks0; x1 += ks1;
#define TF_RND(r) { x0 += x1; x1 = (x1 << (r)) | (x1 >> (32 - (r))); x1 ^= x0; }
  TF_RND(13) TF_RND(15) TF_RND(26) TF_RND(6)
  x0 += ks1; x1 += ks2 + 1u;
  TF_RND(17) TF_RND(29) TF_RND(16) TF_RND(24)
  x0 += ks2; x1 += ks0 + 2u;
  TF_RND(13) TF_RND(15) TF_RND(26) TF_RND(6)
  x0 += ks0; x1 += ks1 + 3u;
  TF_RND(17) TF_RND(29) TF_RND(16) TF_RND(24)
  x0 += ks1; x1 += ks2 + 4u;
  TF_RND(13) TF_RND(15) TF_RND(26) TF_RND(6)
  x0 += ks2; x1 += ks0 + 5u;
#undef TF_RND
  o0 = x0; o1 = x1;
}

// JAX partitionable random_bits(32) for counter (0, cnt); uniform(1e-20,1); gumbel.
__device__ inline float gumbel_noise(uint32_t ka, uint32_t kb, uint32_t cnt) {
  uint32_t o0, o1;
  tf2x32(ka, kb, 0u, cnt, o0, o1);
  uint32_t bits = o0 ^ o1;
  float u = __uint_as_float((bits >> 9) | 0x3F800000u) - 1.0f;
  u = fmaxf(u, 1e-20f);
  return -logf(-logf(u));
}

// ---------------- K1: fully fused per-sample-chunk kernel ----------------
// Block = 4 rows of one sample. Redundantly recomputes the sample's prep in
// LDS (cheap) so no cross-block dependency except BN stats (atomics).
__global__ __launch_bounds__(256, 2) void k_main(
    const float* __restrict__ x, const float* __restrict__ ne,
    const float* __restrict__ lW, const float* __restrict__ lb,
    const float* __restrict__ Ws, const float* __restrict__ bs,
    const float* __restrict__ as_, const float* __restrict__ Wd,
    const float* __restrict__ bd, const float* __restrict__ ad,
    float* __restrict__ o, float* __restrict__ gstat, uint32_t k1a,
    uint32_t k1b, uint32_t k2a, uint32_t k2b) {
  __shared__ float sx[NN][FD];     // sample features, 4 KB
  __shared__ float A[NN * 65];     // nen (normalized node_emb) -> h_s
  __shared__ float Bf[NN * 65];    // nd (normalized dyn emb)   -> h_d
  __shared__ float kks[NN], kkd[NN], dnorm[NN];
  __shared__ float att[4][2][NN];  // per-wave attention rows; reused for stats
  int tid = threadIdx.x, wid = tid >> 6, lane = tid & 63;
  int blk = blockIdx.x;
  int b = blk / 25, rb = (blk % 25) * 4;
  int base = b * NN;
  int r = rb + wid;   // own row (sample-local, == global node index)
  int i = base + r;   // global row
  int j0 = lane, j1 = lane + 64;
  bool v1 = (j1 < NN);
  int jj1 = v1 ? j1 : 0;

  // ---- P0: stage x; stage+normalize node_emb into A (identical math to r2)
  for (int idx = tid; idx < NN * FD; idx += 256)
    ((float*)sx)[idx] = x[base * FD + idx];
  for (int idx = tid; idx < NN * DD; idx += 256)
    A[(idx >> 6) * 65 + (idx & 63)] = ne[idx];
  __syncthreads();
  for (int row = wid; row < NN; row += 4) {
    float v = A[row * 65 + lane];
    float ss = v * v;
    for (int off = 32; off > 0; off >>= 1) ss += __shfl_xor(ss, off, 64);
    if (lane == 0) dnorm[row] = sqrtf(ss) + 1e-8f;
  }
  __syncthreads();
  for (int idx = tid; idx < NN * DD; idx += 256) {
    int row = idx >> 6;
    A[row * 65 + (idx & 63)] /= dnorm[row];
  }
  __syncthreads();

  // ---- P1: static adjacency decisions for own row (registers only)
  bool adj0, adj1;
  {
    float s0 = 0.0f, s1 = 0.0f;
#pragma unroll
    for (int k = 0; k < DD; ++k) {
      float a = A[r * 65 + k];
      s0 = fmaf(a, A[j0 * 65 + k], s0);
      s1 = fmaf(a, A[jj1 * 65 + k], s1);
    }
    int p0 = r * NN + j0;
    float g0 = gumbel_noise(k1a, k1b, (uint32_t)(2 * p0));
    float g1 = gumbel_noise(k1a, k1b, (uint32_t)(2 * p0 + 1));
    adj0 = (s0 + g0 >= 1.0f - s0 + g1) || (r == j0);
    int p1 = r * NN + jj1;
    float g2 = gumbel_noise(k1a, k1b, (uint32_t)(2 * p1));
    float g3 = gumbel_noise(k1a, k1b, (uint32_t)(2 * p1 + 1));
    adj1 = v1 && ((s1 + g2 >= 1.0f - s1 + g3) || (r == j1));
  }

  // ---- P2: prep all 100 rows (h_s->A, nd->Bf, kk arrays, q for own row)
  float wWs[FD], wWd[FD], wlW[FD];
#pragma unroll
  for (int f = 0; f < FD; ++f) {
    wWs[f] = Ws[f * DD + lane];
    wWd[f] = Wd[f * DD + lane];
    wlW[f] = lW[f * DD + lane];
  }
  float vbs = bs[lane], vbd = bd[lane], vlb = lb[lane];
  float a0 = as_[lane], a1 = as_[DD + lane];
  float d0 = ad[lane], d1 = ad[DD + lane];
  float q_s_own = 0.0f, q_d_own = 0.0f;
  __syncthreads();  // P1 reads of A done before overwrite
  for (int row = wid; row < NN; row += 4) {
    float hs = vbs, hd = vbd, ed = vlb;
#pragma unroll
    for (int f = 0; f < FD; ++f) {
      float xv = sx[row][f];
      hs = fmaf(xv, wWs[f], hs);
      hd = fmaf(xv, wWd[f], hd);
      ed = fmaf(xv, wlW[f], ed);
    }
    float ss = ed * ed;
    for (int off = 32; off > 0; off >>= 1) ss += __shfl_xor(ss, off, 64);
    Bf[row * 65 + lane] = ed / (sqrtf(ss) + 1e-8f);
    A[row * 65 + lane] = hs;
    float em = ne[row * DD + lane];
    float ks = hs + em, kd = hd + em;
    float kksv = ks * a1, kkdv = kd * d1;
    for (int off = 32; off > 0; off >>= 1) {
      kksv += __shfl_xor(kksv, off, 64);
      kkdv += __shfl_xor(kkdv, off, 64);
    }
    if (row == r) {  // wave-uniform
      float qsv = ks * a0, qdv = kd * d0;
      for (int off = 32; off > 0; off >>= 1) {
        qsv += __shfl_xor(qsv, off, 64);
        qdv += __shfl_xor(qdv, off, 64);
      }
      q_s_own = qsv;
      q_d_own = qdv;
    }
    if (lane == 0) { kks[row] = kksv; kkd[row] = kkdv; }
  }
  __syncthreads();

  // ---- P3: dynamic edge decisions for own row (registers only)
  bool dadj0, dadj1;
  {
    float s0 = 0.0f, s1 = 0.0f;
#pragma unroll
    for (int k = 0; k < DD; ++k) {
      float a = Bf[r * 65 + k];
      s0 = fmaf(a, Bf[j0 * 65 + k], s0);
      s1 = fmaf(a, Bf[jj1 * 65 + k], s1);
    }
    uint32_t c0 = ((uint32_t)i * 3200u + (uint32_t)(base + j0)) * 2u;
    float g0 = gumbel_noise(k2a, k2b, c0);
    float g1 = gumbel_noise(k2a, k2b, c0 + 1u);
    dadj0 = (s0 + g0 >= 1.0f - s0 + g1);
    uint32_t c1 = ((uint32_t)i * 3200u + (uint32_t)(base + jj1)) * 2u;
    float g2 = gumbel_noise(k2a, k2b, c1);
    float g3 = gumbel_noise(k2a, k2b, c1 + 1u);
    dadj1 = v1 && (s1 + g2 >= 1.0f - s1 + g3);
  }
  __syncthreads();

  // ---- P4: refill Bf with h_d (cheap recompute)
  for (int row = wid; row < NN; row += 4) {
    float hd = vbd;
#pragma unroll
    for (int f = 0; f < FD; ++f) hd = fmaf(sx[row][f], wWd[f], hd);
    Bf[row * 65 + lane] = hd;
  }
  __syncthreads();

  // ---- P5: attention scores + softmaxes + PV (all from LDS)
  float es0 = -9e15f, es1 = -9e15f, ed0 = -9e15f, ed1 = -9e15f;
  if (adj0) {
    float v = q_s_own + kks[j0];
    es0 = (v >= 0.0f) ? v : 0.2f * v;
  }
  if (adj1) {
    float v = q_s_own + kks[j1];
    es1 = (v >= 0.0f) ? v : 0.2f * v;
  }
  if (dadj0) {
    float v = q_d_own + kkd[j0];
    ed0 = (v >= 0.0f) ? v : 0.2f * v;
  }
  if (dadj1) {
    float v = q_d_own + kkd[j1];
    ed1 = (v >= 0.0f) ? v : 0.2f * v;
  }
  // wave softmax, static
  float ms = fmaxf(es0, es1);
  for (int off = 32; off > 0; off >>= 1) ms = fmaxf(ms, __shfl_xor(ms, off, 64));
  float ws0 = expf(es0 - ms);
  float ws1 = v1 ? expf(es1 - ms) : 0.0f;
  float Ss = ws0 + ws1;
  for (int off = 32; off > 0; off >>= 1) Ss += __shfl_xor(Ss, off, 64);
  att[wid][0][j0] = ws0 / Ss;
  if (v1) att[wid][0][j1] = ws1 / Ss;
  // wave softmax, dynamic
  float md = fmaxf(ed0, ed1);
  for (int off = 32; off > 0; off >>= 1) md = fmaxf(md, __shfl_xor(md, off, 64));
  float wd0 = expf(ed0 - md);
  float wd1 = v1 ? expf(ed1 - md) : 0.0f;
  float Sd = wd0 + wd1;
  for (int off = 32; off > 0; off >>= 1) Sd += __shfl_xor(Sd, off, 64);
  att[wid][1][j0] = wd0 / Sd;
  if (v1) att[wid][1][j1] = wd1 / Sd;
  // PV: lane = channel; h_s in A, h_d in Bf
  float hs = 0.0f, hd2 = 0.0f;
#pragma unroll 4
  for (int j = 0; j < NN; ++j) {
    hs = fmaf(att[wid][0][j], A[j * 65 + lane], hs);
    hd2 = fmaf(att[wid][1][j], Bf[j * 65 + lane], hd2);
  }
  float eS = (hs > 0.0f) ? hs : expm1f(hs);
  float eD = (hd2 > 0.0f) ? hd2 : expm1f(hd2);
  float ov = (eS + 0.01f * eD) * ne[r * DD + lane];
  o[i * DD + lane] = ov;

  // ---- P6: BN partials (block reduce + device-scope atomics)
  __syncthreads();
  att[wid][0][lane] = ov;
  att[wid][1][lane] = ov * ov;
  __syncthreads();
  if (wid == 0) {
    float s = att[0][0][lane] + att[1][0][lane] + att[2][0][lane] + att[3][0][lane];
    unsafeAtomicAdd(&gstat[lane], s);
  } else if (wid == 1) {
    float s = att[0][1][lane] + att[1][1][lane] + att[2][1][lane] + att[3][1][lane];
    unsafeAtomicAdd(&gstat[64 + lane], s);
  }
}

// ---------------- K2: BN finalize + apply + ReLU + out projection ----------------
__global__ __launch_bounds__(256) void k_final(
    const float* __restrict__ o, const float* __restrict__ gstat,
    const float* __restrict__ gamma, const float* __restrict__ beta,
    const float* __restrict__ outW, const float* __restrict__ outb,
    float* __restrict__ out) {
  int tid = threadIdx.x, wid = tid >> 6, lane = tid & 63;
  int i = blockIdx.x * 4 + wid;
  float m = gstat[lane] * (1.0f / NT);
  float ex2 = gstat[64 + lane] * (1.0f / NT);
  float var = ex2 - m * m;
  float scale = gamma[lane] / sqrtf(var + 1e-5f);
  float xv = o[i * DD + lane];
  float v = (xv - m) * scale + beta[lane];
  v = fmaxf(v, 0.0f);
  float p = v * outW[lane];
  for (int off = 32; off > 0; off >>= 1) p += __shfl_xor(p, off, 64);
  if (lane == 0) out[i] = p + outb[0];
}

extern "C" void kernel_launch(void* const* d_in, const int* in_sizes, int n_in,
                              void* d_out, int out_size, void* d_ws,
                              size_t ws_size, hipStream_t stream) {
  const float* data = (const float*)d_in[0];
  const float* node_emb = (const float*)d_in[1];
  const float* lin_W = (const float*)d_in[2];
  const float* lin_b = (const float*)d_in[3];
  const float* gat_s_W = (const float*)d_in[4];
  const float* gat_s_b = (const float*)d_in[5];
  const float* gat_s_a = (const float*)d_in[6];
  const float* gat_d_W = (const float*)d_in[7];
  const float* gat_d_b = (const float*)d_in[8];
  const float* gat_d_a = (const float*)d_in[9];
  const float* bn_gamma = (const float*)d_in[10];
  const float* bn_beta = (const float*)d_in[11];
  const float* out_W = (const float*)d_in[12];
  const float* out_b = (const float*)d_in[13];
  float* out = (float*)d_out;

  float* ws = (float*)d_ws;
  float* o = ws;              // NT*DD
  float* gstat = ws + 204800; // 128 (sum[64], sumsq[64])

  // JAX key(42): partitionable split -> k1=cipher(key,(0,0)), k2=cipher(key,(0,1))
  uint32_t k1a, k1b, k2a, k2b;
  tf2x32(0u, 42u, 0u, 0u, k1a, k1b);
  tf2x32(0u, 42u, 0u, 1u, k2a, k2b);

  hipMemsetAsync(gstat, 0, 128 * sizeof(float), stream);
  k_main<<<800, 256, 0, stream>>>(data, node_emb, lin_W, lin_b, gat_s_W,
                                  gat_s_b, gat_s_a, gat_d_W, gat_d_b, gat_d_a,
                                  o, gstat, k1a, k1b, k2a, k2b);
  k_final<<<800, 256, 0, stream>>>(o, gstat, bn_gamma, bn_beta, out_W, out_b,
                                   out);
}